// Round 1
// baseline (156.075 us; speedup 1.0000x reference)
//
#include <hip/hip_runtime.h>

// out[b,i,j] = sum_f input[b,i,j,f] * theta[i,j,f]
// B=64, L=200, F=64.  input: [B, L*L, F] fp32, theta: [L*L, F] fp32,
// out: [B, L*L] fp32.
//
// Strategy: memory-bound streaming dot product.
//  - 16 lanes per output element; lane s loads float4 at f = s*4 (the 16
//    lanes cover the contiguous 256B F-vector -> fully coalesced).
//  - A 256-thread block handles 16 consecutive ij elements for one batch b.
//  - blockIdx swizzle: b is the fastest-varying block coordinate, so 64
//    consecutive blocks share the same 4KB theta chunk (L2 hit).
//  - 4-step __shfl_xor reduce within each 16-lane group.

#define BQ 64          // batch
#define LQ 200
#define FQ 64
#define IJ (LQ * LQ)   // 40000
#define EPB 16         // output elements per block (256 threads / 16 lanes)
#define CHUNKS (IJ / EPB)  // 2500

__global__ __launch_bounds__(256)
void IRLLinearModel_42786464203479_kernel(const float* __restrict__ inp,
                                          const float* __restrict__ theta,
                                          float* __restrict__ out) {
    // b fastest-varying across blocks for theta L2 reuse
    const int chunk = blockIdx.x / BQ;
    const int b     = blockIdx.x % BQ;

    const int g = threadIdx.x >> 4;   // element-within-chunk: 0..15
    const int s = threadIdx.x & 15;   // lane-within-group:    0..15

    const int ij = chunk * EPB + g;   // < 40000 always (2500*16 == 40000)

    const size_t in_off = ((size_t)b * IJ + ij) * FQ + (size_t)s * 4;
    const size_t th_off = (size_t)ij * FQ + (size_t)s * 4;

    const float4 a = *reinterpret_cast<const float4*>(inp + in_off);
    const float4 t = *reinterpret_cast<const float4*>(theta + th_off);

    float p = a.x * t.x + a.y * t.y + a.z * t.z + a.w * t.w;

    // reduce across the 16-lane group (masks < 16 stay inside the group)
    p += __shfl_xor(p, 1);
    p += __shfl_xor(p, 2);
    p += __shfl_xor(p, 4);
    p += __shfl_xor(p, 8);

    if (s == 0) {
        out[(size_t)b * IJ + ij] = p;
    }
}

extern "C" void kernel_launch(void* const* d_in, const int* in_sizes, int n_in,
                              void* d_out, int out_size, void* d_ws, size_t ws_size,
                              hipStream_t stream) {
    const float* inp   = (const float*)d_in[0];
    const float* theta = (const float*)d_in[1];
    float* out = (float*)d_out;

    const int grid = CHUNKS * BQ;  // 160000 blocks
    IRLLinearModel_42786464203479_kernel<<<grid, 256, 0, stream>>>(inp, theta, out);
}

// Round 3
// 135.293 us; speedup vs baseline: 1.1536x; 1.1536x over previous
//
#include <hip/hip_runtime.h>

// out[b,i,j] = sum_f input[b,i,j,f] * theta[i,j,f]
// B=64, L=200, F=64.  input: [B, L*L, F] fp32, theta: [L*L, F] fp32,
// out: [B, L*L] fp32.
//
// Strategy (round 3 — round 2 with compile fix): theta in registers across
// the whole batch loop; 4 independent non-temporal 16B loads in flight.
// __builtin_nontemporal_load needs a Clang ext_vector_type, not HIP float4.

#define BQ 64          // batch
#define LQ 200
#define FQ 64
#define IJ (LQ * LQ)   // 40000
#define EPB 16         // output elements per block (256 threads / 16 lanes)
#define CHUNKS (IJ / EPB)  // 2500

typedef float f32x4 __attribute__((ext_vector_type(4)));

__global__ __launch_bounds__(256)
void IRLLinearModel_42786464203479_kernel(const float* __restrict__ inp,
                                          const float* __restrict__ theta,
                                          float* __restrict__ out) {
    const int chunk = blockIdx.x;

    const int g = threadIdx.x >> 4;   // element-within-chunk: 0..15
    const int s = threadIdx.x & 15;   // lane-within-group:    0..15

    const int ij = chunk * EPB + g;   // 2500*16 == 40000 exactly

    // theta fragment: registers for the whole kernel (read once)
    const f32x4 t = *reinterpret_cast<const f32x4*>(theta + (size_t)ij * FQ + (size_t)s * 4);

    const float* in_base = inp + (size_t)ij * FQ + (size_t)s * 4;
    const size_t bstride = (size_t)IJ * FQ;   // elements between batches

    float* out_base = out + ij;

    #pragma unroll
    for (int b0 = 0; b0 < BQ; b0 += 4) {
        // 4 independent non-temporal loads in flight
        const f32x4 a0 = __builtin_nontemporal_load(
            reinterpret_cast<const f32x4*>(in_base + (size_t)(b0 + 0) * bstride));
        const f32x4 a1 = __builtin_nontemporal_load(
            reinterpret_cast<const f32x4*>(in_base + (size_t)(b0 + 1) * bstride));
        const f32x4 a2 = __builtin_nontemporal_load(
            reinterpret_cast<const f32x4*>(in_base + (size_t)(b0 + 2) * bstride));
        const f32x4 a3 = __builtin_nontemporal_load(
            reinterpret_cast<const f32x4*>(in_base + (size_t)(b0 + 3) * bstride));

        float p0 = a0.x * t.x + a0.y * t.y + a0.z * t.z + a0.w * t.w;
        float p1 = a1.x * t.x + a1.y * t.y + a1.z * t.z + a1.w * t.w;
        float p2 = a2.x * t.x + a2.y * t.y + a2.z * t.z + a2.w * t.w;
        float p3 = a3.x * t.x + a3.y * t.y + a3.z * t.z + a3.w * t.w;

        // reduce across the 16-lane group (masks < 16 stay inside the group)
        p0 += __shfl_xor(p0, 1);  p1 += __shfl_xor(p1, 1);
        p2 += __shfl_xor(p2, 1);  p3 += __shfl_xor(p3, 1);
        p0 += __shfl_xor(p0, 2);  p1 += __shfl_xor(p1, 2);
        p2 += __shfl_xor(p2, 2);  p3 += __shfl_xor(p3, 2);
        p0 += __shfl_xor(p0, 4);  p1 += __shfl_xor(p1, 4);
        p2 += __shfl_xor(p2, 4);  p3 += __shfl_xor(p3, 4);
        p0 += __shfl_xor(p0, 8);  p1 += __shfl_xor(p1, 8);
        p2 += __shfl_xor(p2, 8);  p3 += __shfl_xor(p3, 8);

        if (s == 0) {
            __builtin_nontemporal_store(p0, out_base + (size_t)(b0 + 0) * IJ);
            __builtin_nontemporal_store(p1, out_base + (size_t)(b0 + 1) * IJ);
            __builtin_nontemporal_store(p2, out_base + (size_t)(b0 + 2) * IJ);
            __builtin_nontemporal_store(p3, out_base + (size_t)(b0 + 3) * IJ);
        }
    }
}

extern "C" void kernel_launch(void* const* d_in, const int* in_sizes, int n_in,
                              void* d_out, int out_size, void* d_ws, size_t ws_size,
                              hipStream_t stream) {
    const float* inp   = (const float*)d_in[0];
    const float* theta = (const float*)d_in[1];
    float* out = (float*)d_out;

    IRLLinearModel_42786464203479_kernel<<<CHUNKS, 256, 0, stream>>>(inp, theta, out);
}